// Round 1
// baseline (408.645 us; speedup 1.0000x reference)
//
#include <hip/hip_runtime.h>
#include <hip/hip_bf16.h>

#define N_NODES 50000
#define N_EDGES 800000

// ---------------------------------------------------------------------------
// Degree: deg[dst] += 1  (edge structure is layer-invariant; run once)
// ---------------------------------------------------------------------------
__global__ void deg_kernel(const int* __restrict__ dst, float* __restrict__ deg, int E) {
    int e = blockIdx.x * blockDim.x + threadIdx.x;
    if (e < E) atomicAdd(&deg[dst[e]], 1.0f);
}

// ---------------------------------------------------------------------------
// Edge scatter: agg[dst[e]][f] += ew[e] * h[src[e]][f]
// Thread t -> (e = t/F, f = t%F): F consecutive lanes share an edge, so the
// gather of h[src] rows and the atomic adds to agg[dst] rows are both
// coalesced in F-element chunks.
// ---------------------------------------------------------------------------
template <int F>
__global__ void scatter_kernel(const float* __restrict__ h,
                               const int* __restrict__ src,
                               const int* __restrict__ dst,
                               const float* __restrict__ ew,
                               float* __restrict__ agg, int E) {
    long long t = (long long)blockIdx.x * blockDim.x + threadIdx.x;
    long long total = (long long)E * F;
    if (t >= total) return;
    int e = (int)(t / F);
    int f = (int)(t % F);
    int s = src[e];
    int d = dst[e];
    float w = ew[e];
    atomicAdd(&agg[(long long)d * F + f], w * h[(long long)s * F + f]);
}

// ---------------------------------------------------------------------------
// Dense: out[n][j] = act( b[j] + sum_k h[n][k]*Ws[k][j] + (agg[n][k]/max(deg,1))*Wn[k][j] )
// One thread per (node, out-feature). Weights staged in LDS.
// ---------------------------------------------------------------------------
template <int FIN, int FOUT, bool ACT>
__global__ void dense_kernel(const float* __restrict__ h,
                             const float* __restrict__ agg,
                             const float* __restrict__ deg,
                             const float* __restrict__ Ws,
                             const float* __restrict__ Wn,
                             const float* __restrict__ b,
                             float* __restrict__ out, int N) {
    __shared__ float sWs[FIN * FOUT];
    __shared__ float sWn[FIN * FOUT];
    __shared__ float sb[FOUT];
    for (int i = threadIdx.x; i < FIN * FOUT; i += blockDim.x) {
        sWs[i] = Ws[i];
        sWn[i] = Wn[i];
    }
    for (int i = threadIdx.x; i < FOUT; i += blockDim.x) sb[i] = b[i];
    __syncthreads();

    long long t = (long long)blockIdx.x * blockDim.x + threadIdx.x;
    if (t >= (long long)N * FOUT) return;
    int n = (int)(t / FOUT);
    int j = (int)(t % FOUT);

    float invdeg = 1.0f / fmaxf(deg[n], 1.0f);
    float acc = sb[j];
    const float* __restrict__ hrow = h + (long long)n * FIN;
    const float* __restrict__ arow = agg + (long long)n * FIN;
#pragma unroll
    for (int k = 0; k < FIN; ++k) {
        acc += hrow[k] * sWs[k * FOUT + j] + (arow[k] * invdeg) * sWn[k * FOUT + j];
    }
    out[t] = ACT ? tanhf(acc) : acc;
}

extern "C" void kernel_launch(void* const* d_in, const int* in_sizes, int n_in,
                              void* d_out, int out_size, void* d_ws, size_t ws_size,
                              hipStream_t stream) {
    const float* b_z  = (const float*)d_in[0];   // [50000, 64]
    const int*   src  = (const int*)d_in[1];     // [800000]
    const int*   dst  = (const int*)d_in[2];     // [800000]
    const float* ew   = (const float*)d_in[3];   // [800000]
    const float* Ws0  = (const float*)d_in[4];   // [64,32]
    const float* Wn0  = (const float*)d_in[5];
    const float* b0   = (const float*)d_in[6];
    const float* Ws1  = (const float*)d_in[7];   // [32,16]
    const float* Wn1  = (const float*)d_in[8];
    const float* b1   = (const float*)d_in[9];
    const float* Ws2  = (const float*)d_in[10];  // [16,1]
    const float* Wn2  = (const float*)d_in[11];
    const float* b2   = (const float*)d_in[12];

    const int N = N_NODES;
    const int E = N_EDGES;

    // Workspace layout (floats)
    float* ws   = (float*)d_ws;
    float* deg  = ws;                      // [N]
    float* agg  = deg + N;                 // [N*64] (reused at widths 64/32/16)
    float* h1   = agg + (size_t)N * 64;    // [N*32]
    float* h2   = h1 + (size_t)N * 32;     // [N*16]
    float* outp = (float*)d_out;           // [N*1]

    const int BLK = 256;

    // --- degree (once) ---
    hipMemsetAsync(deg, 0, (size_t)N * sizeof(float), stream);
    deg_kernel<<<(E + BLK - 1) / BLK, BLK, 0, stream>>>(dst, deg, E);

    // --- layer 0: 64 -> 32, tanh ---
    hipMemsetAsync(agg, 0, (size_t)N * 64 * sizeof(float), stream);
    {
        long long total = (long long)E * 64;
        scatter_kernel<64><<<(int)((total + BLK - 1) / BLK), BLK, 0, stream>>>(b_z, src, dst, ew, agg, E);
        long long dt = (long long)N * 32;
        dense_kernel<64, 32, true><<<(int)((dt + BLK - 1) / BLK), BLK, 0, stream>>>(
            b_z, agg, deg, Ws0, Wn0, b0, h1, N);
    }

    // --- layer 1: 32 -> 16, tanh ---
    hipMemsetAsync(agg, 0, (size_t)N * 32 * sizeof(float), stream);
    {
        long long total = (long long)E * 32;
        scatter_kernel<32><<<(int)((total + BLK - 1) / BLK), BLK, 0, stream>>>(h1, src, dst, ew, agg, E);
        long long dt = (long long)N * 16;
        dense_kernel<32, 16, true><<<(int)((dt + BLK - 1) / BLK), BLK, 0, stream>>>(
            h1, agg, deg, Ws1, Wn1, b1, h2, N);
    }

    // --- layer 2: 16 -> 1, linear ---
    hipMemsetAsync(agg, 0, (size_t)N * 16 * sizeof(float), stream);
    {
        long long total = (long long)E * 16;
        scatter_kernel<16><<<(int)((total + BLK - 1) / BLK), BLK, 0, stream>>>(h2, src, dst, ew, agg, E);
        long long dt = (long long)N * 1;
        dense_kernel<16, 1, false><<<(int)((dt + BLK - 1) / BLK), BLK, 0, stream>>>(
            h2, agg, deg, Ws2, Wn2, b2, outp, N);
    }
}

// Round 2
// 245.174 us; speedup vs baseline: 1.6668x; 1.6668x over previous
//
#include <hip/hip_runtime.h>
#include <hip/hip_bf16.h>

#define N_NODES 50000
#define N_EDGES 800000

// ---------------------------------------------------------------------------
// CSR build: count -> exclusive scan -> fill (edge structure is layer-invariant)
// ---------------------------------------------------------------------------
__global__ void count_kernel(const int* __restrict__ dst, int* __restrict__ cnt, int E) {
    int e = blockIdx.x * blockDim.x + threadIdx.x;
    if (e < E) atomicAdd(&cnt[dst[e]], 1);
}

// per-block exclusive scan (Hillis-Steele in LDS), emit block totals
__global__ void scan_block_kernel(const int* __restrict__ in, int* __restrict__ out,
                                  int* __restrict__ blockSums, int n) {
    __shared__ int tmp[256];
    int i = blockIdx.x * 256 + threadIdx.x;
    int v = (i < n) ? in[i] : 0;
    tmp[threadIdx.x] = v;
    __syncthreads();
    for (int off = 1; off < 256; off <<= 1) {
        int t = (threadIdx.x >= (unsigned)off) ? tmp[threadIdx.x - off] : 0;
        __syncthreads();
        tmp[threadIdx.x] += t;
        __syncthreads();
    }
    if (i < n) out[i] = tmp[threadIdx.x] - v;           // exclusive
    if (threadIdx.x == 255) blockSums[blockIdx.x] = tmp[255];
}

// single-block exclusive scan of the (<=256) block sums, in place
__global__ void scan_sums_kernel(int* __restrict__ sums, int nb) {
    __shared__ int tmp[256];
    int v = (threadIdx.x < (unsigned)nb) ? sums[threadIdx.x] : 0;
    tmp[threadIdx.x] = v;
    __syncthreads();
    for (int off = 1; off < 256; off <<= 1) {
        int t = (threadIdx.x >= (unsigned)off) ? tmp[threadIdx.x - off] : 0;
        __syncthreads();
        tmp[threadIdx.x] += t;
        __syncthreads();
    }
    if (threadIdx.x < (unsigned)nb) sums[threadIdx.x] = tmp[threadIdx.x] - v;  // exclusive
}

__global__ void scan_add_kernel(int* __restrict__ out, const int* __restrict__ sums, int n) {
    int i = blockIdx.x * 256 + threadIdx.x;
    if (i < n) out[i] += sums[blockIdx.x];
}

// scatter (src, ew) into dst-sorted buckets
__global__ void fill_kernel(const int* __restrict__ src, const int* __restrict__ dst,
                            const float* __restrict__ ew, int* __restrict__ cursor,
                            int* __restrict__ src_s, float* __restrict__ ew_s, int E) {
    int e = blockIdx.x * blockDim.x + threadIdx.x;
    if (e >= E) return;
    int p = atomicAdd(&cursor[dst[e]], 1);
    src_s[p] = src[e];
    ew_s[p]  = ew[e];
}

// ---------------------------------------------------------------------------
// Pre-multiply: hW[n][j] = sum_k h[n][k] * Wn[k][j]   (so edges carry FOUT wide)
// thread = (node r within block, out-feature j); h rows + Wn staged in LDS
// ---------------------------------------------------------------------------
template <int FIN, int FOUT>
__global__ void premul_kernel(const float* __restrict__ h, const float* __restrict__ Wn,
                              float* __restrict__ hW, int N) {
    constexpr int NPB = 256 / FOUT;
    constexpr int LD  = FIN + 1;           // pad to break bank aliasing
    __shared__ float sW[FIN * FOUT];
    __shared__ float sh[NPB * LD];
    for (int i = threadIdx.x; i < FIN * FOUT; i += 256) sW[i] = Wn[i];
    int nodeBase = blockIdx.x * NPB;
    for (int i = threadIdx.x; i < NPB * FIN; i += 256) {
        int r = i / FIN, k = i % FIN;
        int n = nodeBase + r;
        sh[r * LD + k] = (n < N) ? h[(size_t)n * FIN + k] : 0.f;
    }
    __syncthreads();
    int r = threadIdx.x / FOUT;
    int j = threadIdx.x % FOUT;
    int n = nodeBase + r;
    if (n >= N) return;
    float acc = 0.f;
#pragma unroll
    for (int k = 0; k < FIN; ++k) acc += sh[r * LD + k] * sW[k * FOUT + j];
    hW[(size_t)n * FOUT + j] = acc;
}

// ---------------------------------------------------------------------------
// Fused aggregate + self-transform + bias + activation:
// out[n][j] = act( (1/max(deg,1)) * sum_{e in in(n)} ew_s[e]*hW[src_s[e]][j]
//                  + sum_k h[n][k]*Ws[k][j] + b[j] )
// ---------------------------------------------------------------------------
template <int FIN, int FOUT, bool ACT>
__global__ void agg_post_kernel(const float* __restrict__ h,
                                const float* __restrict__ hW,
                                const int* __restrict__ offs,
                                const int* __restrict__ cnts,
                                const int* __restrict__ src_s,
                                const float* __restrict__ ew_s,
                                const float* __restrict__ Ws,
                                const float* __restrict__ bias,
                                float* __restrict__ out, int N) {
    constexpr int NPB = 256 / FOUT;
    constexpr int LD  = FIN + 1;
    __shared__ float sW[FIN * FOUT];
    __shared__ float sb[FOUT];
    __shared__ float sh[NPB * LD];
    for (int i = threadIdx.x; i < FIN * FOUT; i += 256) sW[i] = Ws[i];
    if (threadIdx.x < FOUT) sb[threadIdx.x] = bias[threadIdx.x];
    int nodeBase = blockIdx.x * NPB;
    for (int i = threadIdx.x; i < NPB * FIN; i += 256) {
        int r = i / FIN, k = i % FIN;
        int n = nodeBase + r;
        sh[r * LD + k] = (n < N) ? h[(size_t)n * FIN + k] : 0.f;
    }
    __syncthreads();
    int r = threadIdx.x / FOUT;
    int j = threadIdx.x % FOUT;
    int n = nodeBase + r;
    if (n >= N) return;

    int beg = offs[n];
    int cnt = cnts[n];
    float nb = 0.f;
    for (int k = 0; k < cnt; ++k) {
        int s = src_s[beg + k];
        nb += ew_s[beg + k] * hW[(size_t)s * FOUT + j];   // coalesced FOUT-chunk gather
    }
    float invdeg = 1.0f / fmaxf((float)cnt, 1.0f);
    float acc = nb * invdeg + sb[j];
#pragma unroll
    for (int k = 0; k < FIN; ++k) acc += sh[r * LD + k] * sW[k * FOUT + j];
    out[(size_t)n * FOUT + j] = ACT ? tanhf(acc) : acc;
}

extern "C" void kernel_launch(void* const* d_in, const int* in_sizes, int n_in,
                              void* d_out, int out_size, void* d_ws, size_t ws_size,
                              hipStream_t stream) {
    const float* b_z = (const float*)d_in[0];   // [50000, 64]
    const int*   src = (const int*)d_in[1];     // [800000]
    const int*   dst = (const int*)d_in[2];     // [800000]
    const float* ew  = (const float*)d_in[3];   // [800000]
    const float* Ws0 = (const float*)d_in[4];   // [64,32]
    const float* Wn0 = (const float*)d_in[5];
    const float* b0  = (const float*)d_in[6];
    const float* Ws1 = (const float*)d_in[7];   // [32,16]
    const float* Wn1 = (const float*)d_in[8];
    const float* b1  = (const float*)d_in[9];
    const float* Ws2 = (const float*)d_in[10];  // [16,1]
    const float* Wn2 = (const float*)d_in[11];
    const float* b2  = (const float*)d_in[12];

    const int N = N_NODES;
    const int E = N_EDGES;
    const int BLK = 256;
    const int NB_N = (N + BLK - 1) / BLK;   // 196 blocks over nodes
    const int NB_E = (E + BLK - 1) / BLK;   // 3125 blocks over edges

    // Workspace layout
    int*   counts = (int*)d_ws;                  // [N]
    int*   offs   = counts + N;                  // [N]
    int*   cursor = offs + N;                    // [N]
    int*   bsums  = cursor + N;                  // [256]
    int*   src_s  = bsums + 256;                 // [E]
    float* ew_s   = (float*)(src_s + E);         // [E]
    float* hW     = ew_s + E;                    // [N*32] (reused at 32/16/1)
    float* h1     = hW + (size_t)N * 32;         // [N*32]
    float* h2     = h1 + (size_t)N * 32;         // [N*16]
    float* outp   = (float*)d_out;               // [N*1]

    // --- CSR build (once per call) ---
    hipMemsetAsync(counts, 0, (size_t)N * sizeof(int), stream);
    count_kernel<<<NB_E, BLK, 0, stream>>>(dst, counts, E);
    scan_block_kernel<<<NB_N, BLK, 0, stream>>>(counts, offs, bsums, N);
    scan_sums_kernel<<<1, BLK, 0, stream>>>(bsums, NB_N);
    scan_add_kernel<<<NB_N, BLK, 0, stream>>>(offs, bsums, N);
    hipMemcpyAsync(cursor, offs, (size_t)N * sizeof(int), hipMemcpyDeviceToDevice, stream);
    fill_kernel<<<NB_E, BLK, 0, stream>>>(src, dst, ew, cursor, src_s, ew_s, E);

    // --- layer 0: 64 -> 32, tanh ---
    premul_kernel<64, 32><<<(N * 32 + BLK - 1) / BLK, BLK, 0, stream>>>(b_z, Wn0, hW, N);
    agg_post_kernel<64, 32, true><<<(N * 32 + BLK - 1) / BLK, BLK, 0, stream>>>(
        b_z, hW, offs, counts, src_s, ew_s, Ws0, b0, h1, N);

    // --- layer 1: 32 -> 16, tanh ---
    premul_kernel<32, 16><<<(N * 16 + BLK - 1) / BLK, BLK, 0, stream>>>(h1, Wn1, hW, N);
    agg_post_kernel<32, 16, true><<<(N * 16 + BLK - 1) / BLK, BLK, 0, stream>>>(
        h1, hW, offs, counts, src_s, ew_s, Ws1, b1, h2, N);

    // --- layer 2: 16 -> 1, linear ---
    premul_kernel<16, 1><<<(N + BLK - 1) / BLK, BLK, 0, stream>>>(h2, Wn2, hW, N);
    agg_post_kernel<16, 1, false><<<(N + BLK - 1) / BLK, BLK, 0, stream>>>(
        h2, hW, offs, counts, src_s, ew_s, Ws2, b2, outp, N);
}

// Round 3
// 226.215 us; speedup vs baseline: 1.8064x; 1.0838x over previous
//
#include <hip/hip_runtime.h>
#include <hip/hip_bf16.h>

#define N_NODES 50000
#define N_EDGES 800000
#define NXCD 8
#define NPX 6250   // nodes per XCD range (50000/8)

// ---------------------------------------------------------------------------
// XCD-partitioned degree count: blocks with bid%8==x own dst range
// [x*NPX, (x+1)*NPX) so atomics stay in one XCD's L2 (no line bouncing).
// ---------------------------------------------------------------------------
__global__ void count_kernel(const int* __restrict__ dst, int* __restrict__ cnt, int E) {
    int xcd = blockIdx.x & (NXCD - 1);
    int s   = blockIdx.x >> 3;
    int nstripes = gridDim.x >> 3;
    int lo = xcd * NPX, hi = lo + NPX;
    for (long long e = (long long)s * blockDim.x + threadIdx.x; e < E;
         e += (long long)nstripes * blockDim.x) {
        int d = dst[e];
        if (d >= lo && d < hi) atomicAdd(&cnt[d], 1);
    }
}

// per-block exclusive scan (Hillis-Steele in LDS), emit block totals
__global__ void scan_block_kernel(const int* __restrict__ in, int* __restrict__ out,
                                  int* __restrict__ blockSums, int n) {
    __shared__ int tmp[256];
    int i = blockIdx.x * 256 + threadIdx.x;
    int v = (i < n) ? in[i] : 0;
    tmp[threadIdx.x] = v;
    __syncthreads();
    for (int off = 1; off < 256; off <<= 1) {
        int t = (threadIdx.x >= (unsigned)off) ? tmp[threadIdx.x - off] : 0;
        __syncthreads();
        tmp[threadIdx.x] += t;
        __syncthreads();
    }
    if (i < n) out[i] = tmp[threadIdx.x] - v;           // exclusive
    if (threadIdx.x == 255) blockSums[blockIdx.x] = tmp[255];
}

// single-block exclusive scan of the (<=256) block sums, in place
__global__ void scan_sums_kernel(int* __restrict__ sums, int nb) {
    __shared__ int tmp[256];
    int v = (threadIdx.x < (unsigned)nb) ? sums[threadIdx.x] : 0;
    tmp[threadIdx.x] = v;
    __syncthreads();
    for (int off = 1; off < 256; off <<= 1) {
        int t = (threadIdx.x >= (unsigned)off) ? tmp[threadIdx.x - off] : 0;
        __syncthreads();
        tmp[threadIdx.x] += t;
        __syncthreads();
    }
    if (threadIdx.x < (unsigned)nb) sums[threadIdx.x] = tmp[threadIdx.x] - v;  // exclusive
}

// add block prefix; also emit cursor copy (saves a d2d memcpy dispatch)
__global__ void scan_add_kernel(int* __restrict__ out, int* __restrict__ cursor,
                                const int* __restrict__ sums, int n) {
    int i = blockIdx.x * 256 + threadIdx.x;
    if (i < n) {
        int v = out[i] + sums[blockIdx.x];
        out[i] = v;
        cursor[i] = v;
    }
}

// ---------------------------------------------------------------------------
// XCD-partitioned CSR fill with packed 8B payload: edge_s[p] = {src, ew}.
// All stores/atomics for a dst range come from one XCD -> lines fill fully.
// ---------------------------------------------------------------------------
__global__ void fill_kernel(const int* __restrict__ src, const int* __restrict__ dst,
                            const float* __restrict__ ew, int* __restrict__ cursor,
                            int2* __restrict__ edge_s, int E) {
    int xcd = blockIdx.x & (NXCD - 1);
    int s   = blockIdx.x >> 3;
    int nstripes = gridDim.x >> 3;
    int lo = xcd * NPX, hi = lo + NPX;
    for (long long e = (long long)s * blockDim.x + threadIdx.x; e < E;
         e += (long long)nstripes * blockDim.x) {
        int d = dst[e];
        if (d >= lo && d < hi) {
            int p = atomicAdd(&cursor[d], 1);
            edge_s[p] = make_int2(src[e], __float_as_int(ew[e]));
        }
    }
}

// ---------------------------------------------------------------------------
// Pre-multiply: hW[n][j] = sum_k h[n][k] * Wn[k][j]   (edges carry FOUT wide)
// ---------------------------------------------------------------------------
template <int FIN, int FOUT>
__global__ void premul_kernel(const float* __restrict__ h, const float* __restrict__ Wn,
                              float* __restrict__ hW, int N) {
    constexpr int NPB = 256 / FOUT;
    constexpr int LD  = FIN + 1;
    __shared__ float sW[FIN * FOUT];
    __shared__ float sh[NPB * LD];
    for (int i = threadIdx.x; i < FIN * FOUT; i += 256) sW[i] = Wn[i];
    int nodeBase = blockIdx.x * NPB;
    for (int i = threadIdx.x; i < NPB * FIN; i += 256) {
        int r = i / FIN, k = i % FIN;
        int n = nodeBase + r;
        sh[r * LD + k] = (n < N) ? h[(size_t)n * FIN + k] : 0.f;
    }
    __syncthreads();
    int r = threadIdx.x / FOUT;
    int j = threadIdx.x % FOUT;
    int n = nodeBase + r;
    if (n >= N) return;
    float acc = 0.f;
#pragma unroll
    for (int k = 0; k < FIN; ++k) acc += sh[r * LD + k] * sW[k * FOUT + j];
    hW[(size_t)n * FOUT + j] = acc;
}

// ---------------------------------------------------------------------------
// Fused aggregate + self-transform + bias + activation.
// ---------------------------------------------------------------------------
template <int FIN, int FOUT, bool ACT>
__global__ void agg_post_kernel(const float* __restrict__ h,
                                const float* __restrict__ hW,
                                const int* __restrict__ offs,
                                const int* __restrict__ cnts,
                                const int2* __restrict__ edge_s,
                                const float* __restrict__ Ws,
                                const float* __restrict__ bias,
                                float* __restrict__ out, int N) {
    constexpr int NPB = 256 / FOUT;
    constexpr int LD  = FIN + 1;
    __shared__ float sW[FIN * FOUT];
    __shared__ float sb[FOUT];
    __shared__ float sh[NPB * LD];
    for (int i = threadIdx.x; i < FIN * FOUT; i += 256) sW[i] = Ws[i];
    if (threadIdx.x < FOUT) sb[threadIdx.x] = bias[threadIdx.x];
    int nodeBase = blockIdx.x * NPB;
    for (int i = threadIdx.x; i < NPB * FIN; i += 256) {
        int r = i / FIN, k = i % FIN;
        int n = nodeBase + r;
        sh[r * LD + k] = (n < N) ? h[(size_t)n * FIN + k] : 0.f;
    }
    __syncthreads();
    int r = threadIdx.x / FOUT;
    int j = threadIdx.x % FOUT;
    int n = nodeBase + r;
    if (n >= N) return;

    int beg = offs[n];
    int cnt = cnts[n];
    float nb = 0.f;
    for (int k = 0; k < cnt; ++k) {
        int2 es = edge_s[beg + k];                       // 8B broadcast load
        nb += __int_as_float(es.y) * hW[(size_t)es.x * FOUT + j];
    }
    float invdeg = 1.0f / fmaxf((float)cnt, 1.0f);
    float acc = nb * invdeg + sb[j];
#pragma unroll
    for (int k = 0; k < FIN; ++k) acc += sh[r * LD + k] * sW[k * FOUT + j];
    out[(size_t)n * FOUT + j] = ACT ? tanhf(acc) : acc;
}

extern "C" void kernel_launch(void* const* d_in, const int* in_sizes, int n_in,
                              void* d_out, int out_size, void* d_ws, size_t ws_size,
                              hipStream_t stream) {
    const float* b_z = (const float*)d_in[0];   // [50000, 64]
    const int*   src = (const int*)d_in[1];     // [800000]
    const int*   dst = (const int*)d_in[2];     // [800000]
    const float* ew  = (const float*)d_in[3];   // [800000]
    const float* Ws0 = (const float*)d_in[4];   // [64,32]
    const float* Wn0 = (const float*)d_in[5];
    const float* b0  = (const float*)d_in[6];
    const float* Ws1 = (const float*)d_in[7];   // [32,16]
    const float* Wn1 = (const float*)d_in[8];
    const float* b1  = (const float*)d_in[9];
    const float* Ws2 = (const float*)d_in[10];  // [16,1]
    const float* Wn2 = (const float*)d_in[11];
    const float* b2  = (const float*)d_in[12];

    const int N = N_NODES;
    const int E = N_EDGES;
    const int BLK = 256;
    const int NB_N = (N + BLK - 1) / BLK;   // 196
    const int GRID_E = 2048;                // 256 stripes per XCD group

    // Workspace layout (all 4B ints/floats; edge_s needs 8B alignment)
    int*   counts = (int*)d_ws;                  // [N]
    int*   offs   = counts + N;                  // [N]
    int*   cursor = offs + N;                    // [N]
    int*   bsums  = cursor + N;                  // [256]
    int2*  edge_s = (int2*)(bsums + 256);        // [E] packed {src, ew}
    float* hW     = (float*)(edge_s + E);        // [N*32] (reused 32/16/1)
    float* h1     = hW + (size_t)N * 32;         // [N*32]
    float* h2     = h1 + (size_t)N * 32;         // [N*16]
    float* outp   = (float*)d_out;               // [N*1]

    // --- CSR build (per call) ---
    hipMemsetAsync(counts, 0, (size_t)N * sizeof(int), stream);
    count_kernel<<<GRID_E, BLK, 0, stream>>>(dst, counts, E);
    scan_block_kernel<<<NB_N, BLK, 0, stream>>>(counts, offs, bsums, N);
    scan_sums_kernel<<<1, BLK, 0, stream>>>(bsums, NB_N);
    scan_add_kernel<<<NB_N, BLK, 0, stream>>>(offs, cursor, bsums, N);
    fill_kernel<<<GRID_E, BLK, 0, stream>>>(src, dst, ew, cursor, edge_s, E);

    // --- layer 0: 64 -> 32, tanh ---
    premul_kernel<64, 32><<<(N * 32 + BLK - 1) / BLK, BLK, 0, stream>>>(b_z, Wn0, hW, N);
    agg_post_kernel<64, 32, true><<<(N * 32 + BLK - 1) / BLK, BLK, 0, stream>>>(
        b_z, hW, offs, counts, edge_s, Ws0, b0, h1, N);

    // --- layer 1: 32 -> 16, tanh ---
    premul_kernel<32, 16><<<(N * 16 + BLK - 1) / BLK, BLK, 0, stream>>>(h1, Wn1, hW, N);
    agg_post_kernel<32, 16, true><<<(N * 16 + BLK - 1) / BLK, BLK, 0, stream>>>(
        h1, hW, offs, counts, edge_s, Ws1, b1, h2, N);

    // --- layer 2: 16 -> 1, linear ---
    premul_kernel<16, 1><<<(N + BLK - 1) / BLK, BLK, 0, stream>>>(h2, Wn2, hW, N);
    agg_post_kernel<16, 1, false><<<(N + BLK - 1) / BLK, BLK, 0, stream>>>(
        h2, hW, offs, counts, edge_s, Ws2, b2, outp, N);
}

// Round 4
// 192.392 us; speedup vs baseline: 2.1240x; 1.1758x over previous
//
#include <hip/hip_runtime.h>
#include <hip/hip_bf16.h>

#define N_NODES 50000
#define N_EDGES 800000
#define NXCD 8
#define NPX 6250   // nodes per XCD range (50000/8)

// ---------------------------------------------------------------------------
// XCD-partitioned degree count: blocks with bid%8==x own dst range
// [x*NPX, (x+1)*NPX) so atomics stay in one XCD's L2 (no line bouncing).
// ---------------------------------------------------------------------------
__global__ void count_kernel(const int* __restrict__ dst, int* __restrict__ cnt, int E) {
    int xcd = blockIdx.x & (NXCD - 1);
    int s   = blockIdx.x >> 3;
    int nstripes = gridDim.x >> 3;
    int lo = xcd * NPX, hi = lo + NPX;
    for (long long e = (long long)s * blockDim.x + threadIdx.x; e < E;
         e += (long long)nstripes * blockDim.x) {
        int d = dst[e];
        if (d >= lo && d < hi) atomicAdd(&cnt[d], 1);
    }
}

// per-block exclusive scan (Hillis-Steele in LDS), emit block totals
__global__ void scan_block_kernel(const int* __restrict__ in, int* __restrict__ out,
                                  int* __restrict__ blockSums, int n) {
    __shared__ int tmp[256];
    int i = blockIdx.x * 256 + threadIdx.x;
    int v = (i < n) ? in[i] : 0;
    tmp[threadIdx.x] = v;
    __syncthreads();
    for (int off = 1; off < 256; off <<= 1) {
        int t = (threadIdx.x >= (unsigned)off) ? tmp[threadIdx.x - off] : 0;
        __syncthreads();
        tmp[threadIdx.x] += t;
        __syncthreads();
    }
    if (i < n) out[i] = tmp[threadIdx.x] - v;           // exclusive
    if (threadIdx.x == 255) blockSums[blockIdx.x] = tmp[255];
}

// single-block exclusive scan of the (<=256) block sums, in place
__global__ void scan_sums_kernel(int* __restrict__ sums, int nb) {
    __shared__ int tmp[256];
    int v = (threadIdx.x < (unsigned)nb) ? sums[threadIdx.x] : 0;
    tmp[threadIdx.x] = v;
    __syncthreads();
    for (int off = 1; off < 256; off <<= 1) {
        int t = (threadIdx.x >= (unsigned)off) ? tmp[threadIdx.x - off] : 0;
        __syncthreads();
        tmp[threadIdx.x] += t;
        __syncthreads();
    }
    if (threadIdx.x < (unsigned)nb) sums[threadIdx.x] = tmp[threadIdx.x] - v;  // exclusive
}

// add block prefix; also emit cursor copy (saves a d2d memcpy dispatch)
__global__ void scan_add_kernel(int* __restrict__ out, int* __restrict__ cursor,
                                const int* __restrict__ sums, int n) {
    int i = blockIdx.x * 256 + threadIdx.x;
    if (i < n) {
        int v = out[i] + sums[blockIdx.x];
        out[i] = v;
        cursor[i] = v;
    }
}

// ---------------------------------------------------------------------------
// XCD-partitioned CSR fill with packed 8B payload: edge_s[p] = {src, ew}.
// ---------------------------------------------------------------------------
__global__ void fill_kernel(const int* __restrict__ src, const int* __restrict__ dst,
                            const float* __restrict__ ew, int* __restrict__ cursor,
                            int2* __restrict__ edge_s, int E) {
    int xcd = blockIdx.x & (NXCD - 1);
    int s   = blockIdx.x >> 3;
    int nstripes = gridDim.x >> 3;
    int lo = xcd * NPX, hi = lo + NPX;
    for (long long e = (long long)s * blockDim.x + threadIdx.x; e < E;
         e += (long long)nstripes * blockDim.x) {
        int d = dst[e];
        if (d >= lo && d < hi) {
            int p = atomicAdd(&cursor[d], 1);
            edge_s[p] = make_int2(src[e], __float_as_int(ew[e]));
        }
    }
}

// ---------------------------------------------------------------------------
// Pre-multiply: hW[n][j] = sum_k h[n][k] * Wn[k][j]   (edges carry FOUT wide)
// ---------------------------------------------------------------------------
template <int FIN, int FOUT>
__global__ void premul_kernel(const float* __restrict__ h, const float* __restrict__ Wn,
                              float* __restrict__ hW, int N) {
    constexpr int NPB = 256 / FOUT;
    constexpr int LD  = FIN + 1;
    __shared__ float sW[FIN * FOUT];
    __shared__ float sh[NPB * LD];
    for (int i = threadIdx.x; i < FIN * FOUT; i += 256) sW[i] = Wn[i];
    int nodeBase = blockIdx.x * NPB;
    for (int i = threadIdx.x; i < NPB * FIN; i += 256) {
        int r = i / FIN, k = i % FIN;
        int n = nodeBase + r;
        sh[r * LD + k] = (n < N) ? h[(size_t)n * FIN + k] : 0.f;
    }
    __syncthreads();
    int r = threadIdx.x / FOUT;
    int j = threadIdx.x % FOUT;
    int n = nodeBase + r;
    if (n >= N) return;
    float acc = 0.f;
#pragma unroll
    for (int k = 0; k < FIN; ++k) acc += sh[r * LD + k] * sW[k * FOUT + j];
    hW[(size_t)n * FOUT + j] = acc;
}

// ---------------------------------------------------------------------------
// Fused aggregate + self-transform + bias + activation, FOUT in {32,16}.
// 8-wide unrolled edge loop: 8 independent edge loads then 8 independent
// hW row gathers in flight -> ~2 latency round-trips per node instead of ~16.
// ---------------------------------------------------------------------------
template <int FIN, int FOUT, bool ACT>
__global__ void agg_post_kernel(const float* __restrict__ h,
                                const float* __restrict__ hW,
                                const int* __restrict__ offs,
                                const int* __restrict__ cnts,
                                const int2* __restrict__ edge_s,
                                const float* __restrict__ Ws,
                                const float* __restrict__ bias,
                                float* __restrict__ out, int N) {
    constexpr int NPB = 256 / FOUT;
    constexpr int LD  = FIN + 1;
    __shared__ float sW[FIN * FOUT];
    __shared__ float sb[FOUT];
    __shared__ float sh[NPB * LD];
    for (int i = threadIdx.x; i < FIN * FOUT; i += 256) sW[i] = Ws[i];
    if (threadIdx.x < FOUT) sb[threadIdx.x] = bias[threadIdx.x];
    int nodeBase = blockIdx.x * NPB;
    for (int i = threadIdx.x; i < NPB * FIN; i += 256) {
        int r = i / FIN, k = i % FIN;
        int n = nodeBase + r;
        sh[r * LD + k] = (n < N) ? h[(size_t)n * FIN + k] : 0.f;
    }
    __syncthreads();
    int r = threadIdx.x / FOUT;
    int j = threadIdx.x % FOUT;
    int n = nodeBase + r;
    if (n >= N) return;

    int beg = offs[n];
    int cnt = cnts[n];
    const int2* __restrict__ ep = edge_s + beg;

    float acc[8];
#pragma unroll
    for (int u = 0; u < 8; ++u) acc[u] = 0.f;

    int k = 0;
    for (; k + 8 <= cnt; k += 8) {
        int2 e[8];
#pragma unroll
        for (int u = 0; u < 8; ++u) e[u] = ep[k + u];      // 8 independent loads
#pragma unroll
        for (int u = 0; u < 8; ++u)                        // 8 independent gathers
            acc[u] += __int_as_float(e[u].y) * hW[(size_t)e[u].x * FOUT + j];
    }
    for (; k < cnt; ++k) {
        int2 e = ep[k];
        acc[0] += __int_as_float(e.y) * hW[(size_t)e.x * FOUT + j];
    }
    float nb = ((acc[0] + acc[1]) + (acc[2] + acc[3])) +
               ((acc[4] + acc[5]) + (acc[6] + acc[7]));

    float invdeg = 1.0f / fmaxf((float)cnt, 1.0f);
    float a = nb * invdeg + sb[j];
#pragma unroll
    for (int kk = 0; kk < FIN; ++kk) a += sh[r * LD + kk] * sW[kk * FOUT + j];
    out[(size_t)n * FOUT + j] = ACT ? tanhf(a) : a;
}

// ---------------------------------------------------------------------------
// Layer 2 (FOUT=1): 16 lanes per node, edge-parallel gather + fused self-dot,
// shuffle-reduce within the 16-lane group. No activation.
// ---------------------------------------------------------------------------
__global__ void agg_final_kernel(const float* __restrict__ h,      // [N,16]
                                 const float* __restrict__ hW,     // [N]
                                 const int* __restrict__ offs,
                                 const int* __restrict__ cnts,
                                 const int2* __restrict__ edge_s,
                                 const float* __restrict__ Ws,     // [16]
                                 const float* __restrict__ bias,   // [1]
                                 float* __restrict__ out, int N) {
    int sub = threadIdx.x & 15;
    int r   = threadIdx.x >> 4;
    int n   = blockIdx.x * 16 + r;
    if (n >= N) return;

    int beg = offs[n];
    int cnt = cnts[n];
    float a = 0.f;
    for (int k = sub; k < cnt; k += 16) {
        int2 e = edge_s[beg + k];
        a += __int_as_float(e.y) * hW[e.x];
    }
    float invdeg = 1.0f / fmaxf((float)cnt, 1.0f);
    // fold neighbor part (scaled) and self-dot slice into one reduce
    float t = a * invdeg + h[(size_t)n * 16 + sub] * Ws[sub];
#pragma unroll
    for (int m = 8; m >= 1; m >>= 1) t += __shfl_xor(t, m, 16);
    if (sub == 0) out[n] = t + bias[0];
}

extern "C" void kernel_launch(void* const* d_in, const int* in_sizes, int n_in,
                              void* d_out, int out_size, void* d_ws, size_t ws_size,
                              hipStream_t stream) {
    const float* b_z = (const float*)d_in[0];   // [50000, 64]
    const int*   src = (const int*)d_in[1];     // [800000]
    const int*   dst = (const int*)d_in[2];     // [800000]
    const float* ew  = (const float*)d_in[3];   // [800000]
    const float* Ws0 = (const float*)d_in[4];   // [64,32]
    const float* Wn0 = (const float*)d_in[5];
    const float* b0  = (const float*)d_in[6];
    const float* Ws1 = (const float*)d_in[7];   // [32,16]
    const float* Wn1 = (const float*)d_in[8];
    const float* b1  = (const float*)d_in[9];
    const float* Ws2 = (const float*)d_in[10];  // [16,1]
    const float* Wn2 = (const float*)d_in[11];
    const float* b2  = (const float*)d_in[12];

    const int N = N_NODES;
    const int E = N_EDGES;
    const int BLK = 256;
    const int NB_N = (N + BLK - 1) / BLK;   // 196
    const int GRID_E = 2048;                // 256 stripes per XCD group

    // Workspace layout
    int*   counts = (int*)d_ws;                  // [N]
    int*   offs   = counts + N;                  // [N]
    int*   cursor = offs + N;                    // [N]
    int*   bsums  = cursor + N;                  // [256]
    int2*  edge_s = (int2*)(bsums + 256);        // [E] packed {src, ew}
    float* hW     = (float*)(edge_s + E);        // [N*32] (reused 32/16/1)
    float* h1     = hW + (size_t)N * 32;         // [N*32]
    float* h2     = h1 + (size_t)N * 32;         // [N*16]
    float* outp   = (float*)d_out;               // [N*1]

    // --- CSR build (per call) ---
    hipMemsetAsync(counts, 0, (size_t)N * sizeof(int), stream);
    count_kernel<<<GRID_E, BLK, 0, stream>>>(dst, counts, E);
    scan_block_kernel<<<NB_N, BLK, 0, stream>>>(counts, offs, bsums, N);
    scan_sums_kernel<<<1, BLK, 0, stream>>>(bsums, NB_N);
    scan_add_kernel<<<NB_N, BLK, 0, stream>>>(offs, cursor, bsums, N);
    fill_kernel<<<GRID_E, BLK, 0, stream>>>(src, dst, ew, cursor, edge_s, E);

    // --- layer 0: 64 -> 32, tanh ---
    premul_kernel<64, 32><<<(N * 32 + BLK - 1) / BLK, BLK, 0, stream>>>(b_z, Wn0, hW, N);
    agg_post_kernel<64, 32, true><<<(N * 32 + BLK - 1) / BLK, BLK, 0, stream>>>(
        b_z, hW, offs, counts, edge_s, Ws0, b0, h1, N);

    // --- layer 1: 32 -> 16, tanh ---
    premul_kernel<32, 16><<<(N * 16 + BLK - 1) / BLK, BLK, 0, stream>>>(h1, Wn1, hW, N);
    agg_post_kernel<32, 16, true><<<(N * 16 + BLK - 1) / BLK, BLK, 0, stream>>>(
        h1, hW, offs, counts, edge_s, Ws1, b1, h2, N);

    // --- layer 2: 16 -> 1, linear ---
    premul_kernel<16, 1><<<(N + BLK - 1) / BLK, BLK, 0, stream>>>(h2, Wn2, hW, N);
    agg_final_kernel<<<(N * 16 + BLK - 1) / BLK, BLK, 0, stream>>>(
        h2, hW, offs, counts, edge_s, Ws2, b2, outp, N);
}

// Round 5
// 183.749 us; speedup vs baseline: 2.2239x; 1.0470x over previous
//
#include <hip/hip_runtime.h>
#include <hip/hip_bf16.h>

#define N_NODES 50000
#define N_EDGES 800000
#define NXCD 8
#define NPX 6250   // nodes per XCD range (50000/8)

// ---------------------------------------------------------------------------
// zero fill (replaces hipMemsetAsync -> rocclr fillBufferAligned dispatch)
// ---------------------------------------------------------------------------
__global__ void zero_kernel(int* __restrict__ p, int n) {
    int i = blockIdx.x * blockDim.x + threadIdx.x;
    if (i < n) p[i] = 0;
}

// ---------------------------------------------------------------------------
// XCD-partitioned degree count: blocks with bid%8==x own dst range
// [x*NPX, (x+1)*NPX) so atomics stay in one XCD's L2 (no line bouncing).
// ---------------------------------------------------------------------------
__global__ void count_kernel(const int* __restrict__ dst, int* __restrict__ cnt, int E) {
    int xcd = blockIdx.x & (NXCD - 1);
    int s   = blockIdx.x >> 3;
    int nstripes = gridDim.x >> 3;
    int lo = xcd * NPX, hi = lo + NPX;
    for (long long e = (long long)s * blockDim.x + threadIdx.x; e < E;
         e += (long long)nstripes * blockDim.x) {
        int d = dst[e];
        if (d >= lo && d < hi) atomicAdd(&cnt[d], 1);
    }
}

// per-block exclusive scan (Hillis-Steele in LDS), emit block totals
__global__ void scan_block_kernel(const int* __restrict__ in, int* __restrict__ out,
                                  int* __restrict__ blockSums, int n) {
    __shared__ int tmp[256];
    int i = blockIdx.x * 256 + threadIdx.x;
    int v = (i < n) ? in[i] : 0;
    tmp[threadIdx.x] = v;
    __syncthreads();
    for (int off = 1; off < 256; off <<= 1) {
        int t = (threadIdx.x >= (unsigned)off) ? tmp[threadIdx.x - off] : 0;
        __syncthreads();
        tmp[threadIdx.x] += t;
        __syncthreads();
    }
    if (i < n) out[i] = tmp[threadIdx.x] - v;           // exclusive
    if (threadIdx.x == 255) blockSums[blockIdx.x] = tmp[255];
}

// single-block exclusive scan of the (<=256) block sums, in place
__global__ void scan_sums_kernel(int* __restrict__ sums, int nb) {
    __shared__ int tmp[256];
    int v = (threadIdx.x < (unsigned)nb) ? sums[threadIdx.x] : 0;
    tmp[threadIdx.x] = v;
    __syncthreads();
    for (int off = 1; off < 256; off <<= 1) {
        int t = (threadIdx.x >= (unsigned)off) ? tmp[threadIdx.x - off] : 0;
        __syncthreads();
        tmp[threadIdx.x] += t;
        __syncthreads();
    }
    if (threadIdx.x < (unsigned)nb) sums[threadIdx.x] = tmp[threadIdx.x] - v;  // exclusive
}

// add block prefix; also emit cursor copy (saves a d2d memcpy dispatch)
__global__ void scan_add_kernel(int* __restrict__ out, int* __restrict__ cursor,
                                const int* __restrict__ sums, int n) {
    int i = blockIdx.x * 256 + threadIdx.x;
    if (i < n) {
        int v = out[i] + sums[blockIdx.x];
        out[i] = v;
        cursor[i] = v;
    }
}

// ---------------------------------------------------------------------------
// XCD-partitioned CSR fill with packed 8B payload: edge_s[p] = {src, ew}.
// ---------------------------------------------------------------------------
__global__ void fill_kernel(const int* __restrict__ src, const int* __restrict__ dst,
                            const float* __restrict__ ew, int* __restrict__ cursor,
                            int2* __restrict__ edge_s, int E) {
    int xcd = blockIdx.x & (NXCD - 1);
    int s   = blockIdx.x >> 3;
    int nstripes = gridDim.x >> 3;
    int lo = xcd * NPX, hi = lo + NPX;
    for (long long e = (long long)s * blockDim.x + threadIdx.x; e < E;
         e += (long long)nstripes * blockDim.x) {
        int d = dst[e];
        if (d >= lo && d < hi) {
            int p = atomicAdd(&cursor[d], 1);
            edge_s[p] = make_int2(src[e], __float_as_int(ew[e]));
        }
    }
}

// ---------------------------------------------------------------------------
// Pre-multiply: hW[n][j] = sum_k h[n][k] * Wn[k][j]; storage type T.
// bf16 storage halves the gather table (layer0: 6.4->3.2MB, fits per-XCD L2).
// ---------------------------------------------------------------------------
template <typename T> __device__ inline T cvt_store(float x);
template <> __device__ inline float cvt_store<float>(float x) { return x; }
template <> __device__ inline __hip_bfloat16 cvt_store<__hip_bfloat16>(float x) {
    return __float2bfloat16(x);
}
__device__ inline float cvt_load(float x) { return x; }
__device__ inline float cvt_load(__hip_bfloat16 x) { return __bfloat162float(x); }

template <int FIN, int FOUT, typename T>
__global__ void premul_kernel(const float* __restrict__ h, const float* __restrict__ Wn,
                              T* __restrict__ hW, int N) {
    constexpr int NPB = 256 / FOUT;
    constexpr int LD  = FIN + 1;
    __shared__ float sW[FIN * FOUT];
    __shared__ float sh[NPB * LD];
    for (int i = threadIdx.x; i < FIN * FOUT; i += 256) sW[i] = Wn[i];
    int nodeBase = blockIdx.x * NPB;
    for (int i = threadIdx.x; i < NPB * FIN; i += 256) {
        int r = i / FIN, k = i % FIN;
        int n = nodeBase + r;
        sh[r * LD + k] = (n < N) ? h[(size_t)n * FIN + k] : 0.f;
    }
    __syncthreads();
    int r = threadIdx.x / FOUT;
    int j = threadIdx.x % FOUT;
    int n = nodeBase + r;
    if (n >= N) return;
    float acc = 0.f;
#pragma unroll
    for (int k = 0; k < FIN; ++k) acc += sh[r * LD + k] * sW[k * FOUT + j];
    hW[(size_t)n * FOUT + j] = cvt_store<T>(acc);
}

// ---------------------------------------------------------------------------
// Fused aggregate + self-transform + bias + activation, FOUT in {32,16}.
// 8-wide unrolled edge loop (8 independent loads -> 8 independent gathers).
// hW is bf16: table is L2-resident, gather lines are half-width.
// ---------------------------------------------------------------------------
template <int FIN, int FOUT, bool ACT>
__global__ void agg_post_kernel(const float* __restrict__ h,
                                const __hip_bfloat16* __restrict__ hW,
                                const int* __restrict__ offs,
                                const int* __restrict__ cnts,
                                const int2* __restrict__ edge_s,
                                const float* __restrict__ Ws,
                                const float* __restrict__ bias,
                                float* __restrict__ out, int N) {
    constexpr int NPB = 256 / FOUT;
    constexpr int LD  = FIN + 1;
    __shared__ float sW[FIN * FOUT];
    __shared__ float sb[FOUT];
    __shared__ float sh[NPB * LD];
    for (int i = threadIdx.x; i < FIN * FOUT; i += 256) sW[i] = Ws[i];
    if (threadIdx.x < FOUT) sb[threadIdx.x] = bias[threadIdx.x];
    int nodeBase = blockIdx.x * NPB;
    for (int i = threadIdx.x; i < NPB * FIN; i += 256) {
        int r = i / FIN, k = i % FIN;
        int n = nodeBase + r;
        sh[r * LD + k] = (n < N) ? h[(size_t)n * FIN + k] : 0.f;
    }
    __syncthreads();
    int r = threadIdx.x / FOUT;
    int j = threadIdx.x % FOUT;
    int n = nodeBase + r;
    if (n >= N) return;

    int beg = offs[n];
    int cnt = cnts[n];
    const int2* __restrict__ ep = edge_s + beg;

    float acc[8];
#pragma unroll
    for (int u = 0; u < 8; ++u) acc[u] = 0.f;

    int k = 0;
    for (; k + 8 <= cnt; k += 8) {
        int2 e[8];
#pragma unroll
        for (int u = 0; u < 8; ++u) e[u] = ep[k + u];      // 8 independent loads
#pragma unroll
        for (int u = 0; u < 8; ++u)                        // 8 independent gathers
            acc[u] += __int_as_float(e[u].y) *
                      __bfloat162float(hW[(size_t)e[u].x * FOUT + j]);
    }
    for (; k < cnt; ++k) {
        int2 e = ep[k];
        acc[0] += __int_as_float(e.y) *
                  __bfloat162float(hW[(size_t)e.x * FOUT + j]);
    }
    float nb = ((acc[0] + acc[1]) + (acc[2] + acc[3])) +
               ((acc[4] + acc[5]) + (acc[6] + acc[7]));

    float invdeg = 1.0f / fmaxf((float)cnt, 1.0f);
    float a = nb * invdeg + sb[j];
#pragma unroll
    for (int kk = 0; kk < FIN; ++kk) a += sh[r * LD + kk] * sW[kk * FOUT + j];
    out[(size_t)n * FOUT + j] = ACT ? tanhf(a) : a;
}

// ---------------------------------------------------------------------------
// Layer 2 (FOUT=1): 16 lanes per node, edge-parallel gather + fused self-dot,
// shuffle-reduce within the 16-lane group. hW stays f32 (200KB, L2-resident).
// ---------------------------------------------------------------------------
__global__ void agg_final_kernel(const float* __restrict__ h,      // [N,16]
                                 const float* __restrict__ hW,     // [N]
                                 const int* __restrict__ offs,
                                 const int* __restrict__ cnts,
                                 const int2* __restrict__ edge_s,
                                 const float* __restrict__ Ws,     // [16]
                                 const float* __restrict__ bias,   // [1]
                                 float* __restrict__ out, int N) {
    int sub = threadIdx.x & 15;
    int r   = threadIdx.x >> 4;
    int n   = blockIdx.x * 16 + r;
    if (n >= N) return;

    int beg = offs[n];
    int cnt = cnts[n];
    float a = 0.f;
    for (int k = sub; k < cnt; k += 16) {
        int2 e = edge_s[beg + k];
        a += __int_as_float(e.y) * hW[e.x];
    }
    float invdeg = 1.0f / fmaxf((float)cnt, 1.0f);
    float t = a * invdeg + h[(size_t)n * 16 + sub] * Ws[sub];
#pragma unroll
    for (int m = 8; m >= 1; m >>= 1) t += __shfl_xor(t, m, 16);
    if (sub == 0) out[n] = t + bias[0];
}

extern "C" void kernel_launch(void* const* d_in, const int* in_sizes, int n_in,
                              void* d_out, int out_size, void* d_ws, size_t ws_size,
                              hipStream_t stream) {
    const float* b_z = (const float*)d_in[0];   // [50000, 64]
    const int*   src = (const int*)d_in[1];     // [800000]
    const int*   dst = (const int*)d_in[2];     // [800000]
    const float* ew  = (const float*)d_in[3];   // [800000]
    const float* Ws0 = (const float*)d_in[4];   // [64,32]
    const float* Wn0 = (const float*)d_in[5];
    const float* b0  = (const float*)d_in[6];
    const float* Ws1 = (const float*)d_in[7];   // [32,16]
    const float* Wn1 = (const float*)d_in[8];
    const float* b1  = (const float*)d_in[9];
    const float* Ws2 = (const float*)d_in[10];  // [16,1]
    const float* Wn2 = (const float*)d_in[11];
    const float* b2  = (const float*)d_in[12];

    const int N = N_NODES;
    const int E = N_EDGES;
    const int BLK = 256;
    const int NB_N = (N + BLK - 1) / BLK;   // 196
    const int GRID_E = 2048;                // 256 stripes per XCD group

    // Workspace layout
    int*   counts = (int*)d_ws;                    // [N]
    int*   offs   = counts + N;                    // [N]
    int*   cursor = offs + N;                      // [N]
    int*   bsums  = cursor + N;                    // [256]
    int2*  edge_s = (int2*)(bsums + 256);          // [E] packed {src, ew}
    float* fbase  = (float*)(edge_s + E);
    __hip_bfloat16* hWb = (__hip_bfloat16*)fbase;  // [N*32] bf16 (layers 0/1)
    float* hWf    = fbase;                          // [N] f32 (layer 2; aliases hWb, used serially)
    float* h1     = fbase + (size_t)N * 32;        // [N*32] f32
    float* h2     = h1 + (size_t)N * 32;           // [N*16] f32
    float* outp   = (float*)d_out;                 // [N*1]

    // --- CSR build (per call) ---
    zero_kernel<<<NB_N, BLK, 0, stream>>>(counts, N);
    count_kernel<<<GRID_E, BLK, 0, stream>>>(dst, counts, E);
    scan_block_kernel<<<NB_N, BLK, 0, stream>>>(counts, offs, bsums, N);
    scan_sums_kernel<<<1, BLK, 0, stream>>>(bsums, NB_N);
    scan_add_kernel<<<NB_N, BLK, 0, stream>>>(offs, cursor, bsums, N);
    fill_kernel<<<GRID_E, BLK, 0, stream>>>(src, dst, ew, cursor, edge_s, E);

    // --- layer 0: 64 -> 32, tanh ---
    premul_kernel<64, 32, __hip_bfloat16><<<(N * 32 + BLK - 1) / BLK, BLK, 0, stream>>>(
        b_z, Wn0, hWb, N);
    agg_post_kernel<64, 32, true><<<(N * 32 + BLK - 1) / BLK, BLK, 0, stream>>>(
        b_z, hWb, offs, counts, edge_s, Ws0, b0, h1, N);

    // --- layer 1: 32 -> 16, tanh ---
    premul_kernel<32, 16, __hip_bfloat16><<<(N * 16 + BLK - 1) / BLK, BLK, 0, stream>>>(
        h1, Wn1, hWb, N);
    agg_post_kernel<32, 16, true><<<(N * 16 + BLK - 1) / BLK, BLK, 0, stream>>>(
        h1, hWb, offs, counts, edge_s, Ws1, b1, h2, N);

    // --- layer 2: 16 -> 1, linear (hW stays f32) ---
    premul_kernel<16, 1, float><<<(N + BLK - 1) / BLK, BLK, 0, stream>>>(h2, Wn2, hWf, N);
    agg_final_kernel<<<(N * 16 + BLK - 1) / BLK, BLK, 0, stream>>>(
        h2, hWf, offs, counts, edge_s, Ws2, b2, outp, N);
}